// Round 7
// baseline (119.311 us; speedup 1.0000x reference)
//
#include <hip/hip_runtime.h>

typedef float f32x2 __attribute__((ext_vector_type(2)));
typedef float f32x4 __attribute__((ext_vector_type(4)));

#define PAD 3
#define HH 320
#define WW 1024
#define BB 8
#define TH 32
#define TW 64
#define LDS_W  72             // 4 left halo + 64 + 4 right halo, 16B-aligned
#define NF4    (LDS_W/4)      // 18 float4 per staged row
#define RPW 8                 // rows per wave
#define NWAVES 4
#define NTHREADS 256
#define WROWS (RPW + 6)       // wave-private halo rows: li0-3 .. li0+10
#define NPOSW (WROWS * NF4)   // 252 float4 positions per wave per plane

#define NIN ((HH - 2*PAD) * (WW - 2*PAD))
#define OUT_SCALE (1.0 / (49.0 * (double)BB * (double)HH * (double)WW))
#define C0 ((float)(48.0 * (double)BB * (double)NIN * OUT_SCALE))
#define NEG_SCALE ((float)(-0.1 * OUT_SCALE))

// keep a value pinned in a VGPR (defeat LDS-load rematerialization)
#define KEEP(v) asm("" : "+v"(v))

static __device__ __forceinline__ f32x2 mk2(float a, float b){ f32x2 r; r.x=a; r.y=b; return r; }
static __device__ __forceinline__ f32x2 sp2(float a){ f32x2 r; r.x=a; r.y=a; return r; }
static __device__ __forceinline__ f32x2 fma2(f32x2 a, f32x2 b, f32x2 c){
    return __builtin_elementwise_fma(a, b, c);
}

// Two offsets at once (compiler-lowered f32x2; verified exact, absmax 0).
//   t^2 = s*(s*A - 2*dx*dy), s=rsq(ax*ay), A=dx^2*ay+dy^2*ax, a*=0.81+d*^2
//   w1/(0.1+t1^2)+w2/(0.1+t2^2) = rcp(b1*b2)*(w1*b2+w2*b1);  INTERIOR: w==2
template<bool INTERIOR>
static __device__ __forceinline__ void pair2(f32x2 nx, f32x2 ny, f32x2 cx2, f32x2 cy2,
                                             f32x2 w2, float& acc)
{
    f32x2 dx  = nx - cx2;
    f32x2 dy  = ny - cy2;
    f32x2 dx2 = dx * dx;
    f32x2 dy2 = dy * dy;
    f32x2 ax  = dx2 + sp2(0.81f);
    f32x2 ay  = dy2 + sp2(0.81f);
    f32x2 P   = ax * ay;
    f32x2 s; s.x = __builtin_amdgcn_rsqf(P.x); s.y = __builtin_amdgcn_rsqf(P.y);
    f32x2 A   = fma2(dx2, ay, dy2 * ax);
    f32x2 h   = dx * dy;
    f32x2 inner = fma2(s, A, h * sp2(-2.0f));
    f32x2 t2  = s * inner;
    f32x2 den = t2 + sp2(0.1f);
    float ip  = __builtin_amdgcn_rcpf(den.x * den.y);
    float cross;
    if constexpr (INTERIOR) cross = den.x + den.y;
    else                    cross = fmaf(w2.x, den.y, w2.y * den.x);
    acc = fmaf(ip, cross, acc);
}

// compute this wave's 8 output rows from its PRIVATE staged region
template<bool INTERIOR>
static __device__ __forceinline__ float compute_rows(
    const float (&sx)[WROWS][LDS_W], const float (&sy)[WROWS][LDS_W],
    int tile_i, int tile_j, int tx, int li0)
{
    float cO3 = 0.0f;
    f32x2 cP0 = {}, cP1 = {}, cP2 = {}, cP3 = {};
    if constexpr (!INTERIOR) {
        float cO[7];
        const int gj = tile_j + tx;
        #pragma unroll
        for (int d = 0; d < 7; ++d) {
            int nj = gj + d - 3;
            cO[d] = (nj >= PAD && nj < WW - PAD) ? 1.0f : 0.0f;
        }
        cP0 = mk2(cO[0], cO[1]);
        cP1 = mk2(cO[2], cO[3]);
        cP2 = mk2(cO[4], cO[5]);
        cP3 = sp2(cO[6]);
        cO3 = cO[3];
    }

    // local row k holds pixel row li0 + k - 3; output row li -> pixel rows
    // li..li+3 -> local rows (li-li0)+3 .. (li-li0)+6
    float wx[4][7], wy[4][7];
    #pragma unroll
    for (int r = 0; r < 3; ++r) {
        #pragma unroll
        for (int d = 0; d < 7; ++d) {
            float a = sx[3 + r][tx + 1 + d]; KEEP(a); wx[r][d] = a;
            float c = sy[3 + r][tx + 1 + d]; KEEP(c); wy[r][d] = c;
        }
    }

    float acc = 0.0f;

    #pragma unroll 1
    for (int io = 0; io < RPW / 4; ++io) {
        #pragma unroll
        for (int iu = 0; iu < 4; ++iu) {
            const int lr = io * 4 + iu;            // 0..7 within strip
            const int gi = tile_i + li0 + lr;      // global pixel row
            const int sn = (iu + 3) & 3;
            #pragma unroll
            for (int d = 0; d < 7; ++d) {
                float a = sx[lr + 6][tx + 1 + d]; KEEP(a); wx[sn][d] = a;
                float c = sy[lr + 6][tx + 1 + d]; KEEP(c); wy[sn][d] = c;
            }

            float rin[4] = {};
            f32x2 mc2 = {};
            if constexpr (!INTERIOR) {
                #pragma unroll
                for (int di = 0; di < 4; ++di) {
                    int ni = gi + di;
                    rin[di] = (ni >= PAD && ni < HH - PAD) ? 1.0f : 0.0f;
                }
                mc2 = sp2(rin[0] * cO3);
            }

            const int s0 = iu & 3, s1 = (iu+1)&3, s2 = (iu+2)&3, s3_ = (iu+3)&3;
            const f32x2 cx2 = sp2(wx[s0][3]);
            const f32x2 cy2 = sp2(wy[s0][3]);

            // di = 0, dj = +1,+2
            pair2<INTERIOR>(mk2(wx[s0][4], wx[s0][5]), mk2(wy[s0][4], wy[s0][5]),
                cx2, cy2, INTERIOR ? sp2(0.0f) : fma2(sp2(rin[0]), cP2, mc2), acc);

            // di = 1..3: dj-pair groups A(-3,-2), B(-1,0), C(+1,+2)
            #pragma unroll
            for (int di = 1; di <= 3; ++di) {
                const int s = (iu + di) & 3;
                const f32x2 rin2 = sp2(rin[di]);
                pair2<INTERIOR>(mk2(wx[s][0], wx[s][1]), mk2(wy[s][0], wy[s][1]),
                    cx2, cy2, INTERIOR ? sp2(0.0f) : fma2(rin2, cP0, mc2), acc);
                pair2<INTERIOR>(mk2(wx[s][2], wx[s][3]), mk2(wy[s][2], wy[s][3]),
                    cx2, cy2, INTERIOR ? sp2(0.0f) : fma2(rin2, cP1, mc2), acc);
                pair2<INTERIOR>(mk2(wx[s][4], wx[s][5]), mk2(wy[s][4], wy[s][5]),
                    cx2, cy2, INTERIOR ? sp2(0.0f) : fma2(rin2, cP2, mc2), acc);
            }

            // leftovers dj = +3, packed across di: (0,1) and (2,3)
            pair2<INTERIOR>(mk2(wx[s0][6], wx[s1][6]), mk2(wy[s0][6], wy[s1][6]),
                cx2, cy2, INTERIOR ? sp2(0.0f) : fma2(mk2(rin[0], rin[1]), cP3, mc2), acc);
            pair2<INTERIOR>(mk2(wx[s2][6], wx[s3_][6]), mk2(wy[s2][6], wy[s3_][6]),
                cx2, cy2, INTERIOR ? sp2(0.0f) : fma2(mk2(rin[2], rin[3]), cP3, mc2), acc);
        }
    }

    return acc;
}

__global__ __launch_bounds__(NTHREADS, 4) void ternary_loss_kernel(
    const float* __restrict__ x, const float* __restrict__ y,
    float* __restrict__ out)
{
    // wave-PRIVATE halo regions: no inter-wave sharing -> no __syncthreads
    // between staging and compute; waves de-phase and pipeline naturally.
    __shared__ __align__(16) float sIx[NWAVES][WROWS][LDS_W];
    __shared__ __align__(16) float sIy[NWAVES][WROWS][LDS_W];
    __shared__ float wave_sums[NWAVES];

    const int tile_j = blockIdx.x * TW;
    const int tile_i = blockIdx.y * TH;
    const int b      = blockIdx.z;
    const int tx  = threadIdx.x;            // 0..63
    const int wv  = threadIdx.y;            // 0..3
    const int tid = wv * 64 + tx;

    const size_t PLANE = (size_t)HH * WW;
    const float* xb = x + (size_t)b * 3 * PLANE;
    const float* yb = y + (size_t)b * 3 * PLANE;

    const int li0 = wv * RPW;               // this wave's first output row

    // ---- stage this wave's 14 halo rows into its private LDS region ----
    for (int p = tx; p < NPOSW; p += 64) {
        int r  = p / NF4;                   // local row 0..13
        int c4 = p - r * NF4;
        int gi  = tile_i + li0 - 3 + r;     // global pixel row
        int gj0 = tile_j - 4 + 4 * c4;
        f32x4 vx = {0.0f, 0.0f, 0.0f, 0.0f};
        f32x4 vy = {0.0f, 0.0f, 0.0f, 0.0f};
        if ((unsigned)gi < (unsigned)HH && (unsigned)gj0 < (unsigned)WW) {
            const float* px = xb + (size_t)gi * WW + gj0;
            f32x4 a0 = *(const f32x4*)(px);
            f32x4 a1 = *(const f32x4*)(px + PLANE);
            f32x4 a2 = *(const f32x4*)(px + 2 * PLANE);
            vx = (a0 + a1 + a2) * (1.0f / 3.0f);
            const float* py = yb + (size_t)gi * WW + gj0;
            f32x4 b0 = *(const f32x4*)(py);
            f32x4 b1 = *(const f32x4*)(py + PLANE);
            f32x4 b2 = *(const f32x4*)(py + 2 * PLANE);
            vy = (b0 + b1 + b2) * (1.0f / 3.0f);
        }
        *(f32x4*)&sIx[wv][r][4 * c4] = vx;
        *(f32x4*)&sIy[wv][r][4 * c4] = vy;
    }
    // NO __syncthreads: each wave consumes only its own region; the compiler
    // inserts the wave-local lgkmcnt wait before the first window read.

    // block-uniform interior test (verified exact, absmax 0)
    const bool interior = (tile_i >= PAD) && (tile_i + TH + PAD <= HH - PAD)
                       && (tile_j >= 2*PAD) && (tile_j + TW + PAD <= WW - PAD);

    float acc;
    if (interior)
        acc = 2.0f * compute_rows<true >(sIx[wv], sIy[wv], tile_i, tile_j, tx, li0);
    else
        acc =        compute_rows<false>(sIx[wv], sIy[wv], tile_i, tile_j, tx, li0);

    // ---- reduction: wave shuffle -> LDS across 4 waves -> one atomic ----
    #pragma unroll
    for (int off = 32; off > 0; off >>= 1)
        acc += __shfl_down(acc, off, 64);
    if (tx == 0) wave_sums[wv] = acc;
    __syncthreads();
    if (tid == 0) {
        float total = (wave_sums[0] + wave_sums[1] + wave_sums[2] + wave_sums[3]) * NEG_SCALE;
        if (blockIdx.x == 0 && blockIdx.y == 0 && blockIdx.z == 0)
            total += C0;                       // analytic  sum(w)*1  term, added once
        atomicAdd(out, total);
    }
}

extern "C" void kernel_launch(void* const* d_in, const int* in_sizes, int n_in,
                              void* d_out, int out_size, void* d_ws, size_t ws_size,
                              hipStream_t stream) {
    const float* x = (const float*)d_in[0];
    const float* y = (const float*)d_in[1];
    float* out = (float*)d_out;

    hipMemsetAsync(out, 0, sizeof(float), stream);

    dim3 grid(WW / TW, HH / TH, BB);   // 16 x 10 x 8 = 1280 blocks
    dim3 block(64, NWAVES, 1);
    ternary_loss_kernel<<<grid, block, 0, stream>>>(x, y, out);
}